// Round 1
// baseline (1213.799 us; speedup 1.0000x reference)
//
#include <hip/hip_runtime.h>
#include <cstddef>
#include <cstdint>

typedef _Float16 h4 __attribute__((ext_vector_type(4)));
typedef _Float16 h8 __attribute__((ext_vector_type(8)));
typedef float    f4 __attribute__((ext_vector_type(4)));

#define NN      50000
#define IND     512
#define HIDN    256
#define E2P     400000
#define EDD     800000

// ---- workspace layout (bytes) ----
#define OFF_HF16    ((size_t)0)            // 25,600,000  f16 h [NN][256]
#define OFF_LOGPHI  ((size_t)25600000)     //  1,600,000  f32 [NN][8]
#define OFF_DEG     ((size_t)27200000)     //    200,000  int [NN]
#define OFF_LOGDEG  ((size_t)27400000)     //    200,000  f32
#define OFF_DEGC    ((size_t)27600000)     //    200,000  f32
#define OFF_WT      ((size_t)27800000)     //    262,144  f16 enc_w1^T [256][512]
#define OFF_BT      ((size_t)28062144)     //     69,632  f16 edge_w1 perm^T [64][544]
#define OFF_RS      ((size_t)28131776)     //        512  f32 Rs[64] + alpha at [64]
#define OFF_WHALF   ((size_t)28132288)     //  3,200,000  f32 [EDD]
#define OFF_WSYM    ((size_t)31332288)     //  1,600,000  f32 [E2P]
#define OFF_ENORM   ((size_t)32932288)     //  1,600,000  f32 [E2P]
#define OFF_MA      ((size_t)34532288)     // 25,600,000  f32 [EDD][8]
#define OFF_MB      ((size_t)60132288)     // 25,600,000
#define OFF_SUMIN   ((size_t)85732288)     //  1,600,000  f32 [NN][8]
#define WS_NEED     ((size_t)87332288)

// ---------------- degree count ----------------
__global__ void k_deg(const int* __restrict__ ei, int* __restrict__ deg) {
    int e = blockIdx.x * 256 + threadIdx.x;   // grid exact: EDD
    atomicAdd(&deg[ei[e]], 1);
}

__global__ void k_node(const int* __restrict__ deg, float* __restrict__ logdeg,
                       float* __restrict__ degc) {
    int n = blockIdx.x * 256 + threadIdx.x;
    if (n < NN) {
        float d = (float)deg[n];
        logdeg[n] = logf(d + 1.0f);
        degc[n]   = fmaxf(d, 1.0f);
    }
}

// ---------------- weight prep: transpose/permute/cast + R + alpha ----------------
__global__ void k_prep(const float* __restrict__ enc_w1, const float* __restrict__ edge_w1,
                       const float* __restrict__ R_raw, const float* __restrict__ Rsl,
                       const float* __restrict__ mlog,
                       _Float16* __restrict__ Wt, _Float16* __restrict__ Bt,
                       float* __restrict__ Rs) {
    int gid = blockIdx.x * 256 + threadIdx.x;
    if (gid < 256 * 512) {                       // Wt[n][k] = enc_w1[k][n]
        int n = gid >> 9, k = gid & 511;
        Wt[n * 512 + k] = (_Float16)enc_w1[k * 256 + n];
        return;
    }
    int g2 = gid - 256 * 512;
    if (g2 < 64 * 544) {                         // Bt[n][k'] with interleaved K perm
        int n = g2 / 544, k = g2 - n * 544;
        float v = 0.0f;
        if (k < 512) {
            int orig = (k & 1) ? 256 + (k >> 1) : (k >> 1);
            v = edge_w1[orig * 64 + n];
        } else if (k < 514) {
            v = edge_w1[k * 64 + n];
        }
        Bt[n * 544 + k] = (_Float16)v;
        return;
    }
    int g3 = g2 - 64 * 544;
    if (g3 < 64) {
        int c = g3 >> 3, d = g3 & 7;
        float rv = 0.5f * (R_raw[c * 8 + d] + R_raw[d * 8 + c]);
        float s  = log1pf(expf(Rsl[0])) + 1e-6f; // softplus + eps
        Rs[g3] = s * tanhf(rv);
        return;
    }
    if (g3 == 64) {
        Rs[64] = 1.5f / (1.0f + expf(-mlog[0])); // alpha = ALPHA_MAX*sigmoid(msg_logit)
    }
}

// ---------------- encoder layer 1: h = relu(x @ enc_w1 + b1), f16 MFMA ----------------
__global__ __launch_bounds__(256) void k_enc(const float* __restrict__ x,
                                             const _Float16* __restrict__ Wt,
                                             const float* __restrict__ b1,
                                             _Float16* __restrict__ hf) {
    __shared__ _Float16 XL[64 * 40];
    __shared__ _Float16 WL[256 * 40];
    const int tid = threadIdx.x;
    const int wid = tid >> 6;
    const int lane = tid & 63;
    const int l15 = lane & 15;
    const int q = lane >> 4;
    const int m0 = blockIdx.x * 64;

    f4 acc[16];
#pragma unroll
    for (int i = 0; i < 16; i++) acc[i] = (f4){0.f, 0.f, 0.f, 0.f};

    const int xr = tid >> 2;
    const int xs = tid & 3;
    const int gr = m0 + xr;

    for (int kt = 0; kt < 16; kt++) {
        __syncthreads();
        f4 xv0 = (f4){0, 0, 0, 0}, xv1 = (f4){0, 0, 0, 0};
        if (gr < NN) {
            const f4* xp = (const f4*)(x + (size_t)gr * IND + kt * 32 + xs * 8);
            xv0 = xp[0]; xv1 = xp[1];
        }
        h8 xh;
#pragma unroll
        for (int u = 0; u < 4; u++) { xh[u] = (_Float16)xv0[u]; xh[4 + u] = (_Float16)xv1[u]; }
        *(h8*)&XL[xr * 40 + xs * 8] = xh;
#pragma unroll
        for (int rep = 0; rep < 4; rep++) {
            int cid = rep * 256 + tid;
            int n = cid >> 2;
            int off = (cid & 3) * 8;
            h8 wv = *(const h8*)(Wt + (size_t)n * IND + kt * 32 + off);
            *(h8*)&WL[n * 40 + off] = wv;
        }
        __syncthreads();
        h8 a = *(const h8*)&XL[(wid * 16 + l15) * 40 + q * 8];
#pragma unroll
        for (int nt = 0; nt < 16; nt++) {
            h8 b = *(const h8*)&WL[(nt * 16 + l15) * 40 + q * 8];
            acc[nt] = __builtin_amdgcn_mfma_f32_16x16x32_f16(a, b, acc[nt], 0, 0, 0);
        }
    }
#pragma unroll
    for (int nt = 0; nt < 16; nt++) {
        int col = nt * 16 + l15;
        float bv = b1[col];
#pragma unroll
        for (int reg = 0; reg < 4; reg++) {
            int row = m0 + wid * 16 + q * 4 + reg;
            if (row < NN) {
                float v = acc[nt][reg] + bv;
                hf[(size_t)row * HIDN + col] = (_Float16)fmaxf(v, 0.f);
            }
        }
    }
}

// ---------------- encoder layer 2 + log_softmax, thread per node ----------------
__global__ void k_logits(const _Float16* __restrict__ hf, const float* __restrict__ w2,
                         const float* __restrict__ b2, float* __restrict__ log_phi) {
    __shared__ float w2L[2048];
    for (int i = threadIdx.x; i < 2048; i += 256) w2L[i] = w2[i];
    __syncthreads();
    int n = blockIdx.x * 256 + threadIdx.x;
    if (n >= NN) return;
    float sum[8];
#pragma unroll
    for (int c = 0; c < 8; c++) sum[c] = b2[c];
    for (int kb = 0; kb < 32; kb++) {
        h8 hv = *(const h8*)(hf + (size_t)n * HIDN + kb * 8);
#pragma unroll
        for (int u = 0; u < 8; u++) {
            float hx = (float)hv[u];
            const float* wr = &w2L[(kb * 8 + u) * 8];
#pragma unroll
            for (int c = 0; c < 8; c++) sum[c] += hx * wr[c];
        }
    }
    float mx = sum[0];
#pragma unroll
    for (int c = 1; c < 8; c++) mx = fmaxf(mx, sum[c]);
    float se = 0.f;
#pragma unroll
    for (int c = 0; c < 8; c++) se += __expf(sum[c] - mx);
    float lse = __logf(se);
#pragma unroll
    for (int c = 0; c < 8; c++) log_phi[(size_t)n * 8 + c] = sum[c] - mx - lse;
}

// ---------------- edge MLP: fused gather + f16 MFMA GEMM ----------------
__global__ __launch_bounds__(256) void k_edge(const int* __restrict__ ei,
        const _Float16* __restrict__ hf, const float* __restrict__ logdeg,
        const _Float16* __restrict__ BtG, const float* __restrict__ eb1,
        const float* __restrict__ ew2, const float* __restrict__ eb2,
        float* __restrict__ w_half) {
    __shared__ _Float16 BtL[64 * 296];
    const int tid = threadIdx.x;
    const int wid = tid >> 6;
    const int lane = tid & 63;
    const int l15 = lane & 15;
    const int q = lane >> 4;
    const int eb = blockIdx.x * 256;

    int sidx[4], didx[4];
    float la[4], lb[4];
#pragma unroll
    for (int mt = 0; mt < 4; mt++) {
        int e = eb + wid * 64 + mt * 16 + l15;
        sidx[mt] = ei[e];
        didx[mt] = ei[EDD + e];
        la[mt] = logdeg[sidx[mt]];
        lb[mt] = logdeg[didx[mt]];
    }

    f4 acc[4][4];
#pragma unroll
    for (int a = 0; a < 4; a++)
#pragma unroll
        for (int b = 0; b < 4; b++) acc[a][b] = (f4){0.f, 0.f, 0.f, 0.f};

    for (int phase = 0; phase < 2; phase++) {
        const int kbase = phase ? 288 : 0;
        const int nch = phase ? 32 : 36;   // 16B chunks per row of Bt slab
        __syncthreads();
        {
            const int n = tid & 63;
            const int cb = tid >> 6;
            for (int ck = cb; ck < nch; ck += 4) {
                h8 v = *(const h8*)(BtG + (size_t)n * 544 + kbase + ck * 8);
                *(h8*)&BtL[n * 296 + ck * 8] = v;
            }
        }
        __syncthreads();
        const int kt0 = phase ? 9 : 0;
        const int kt1 = phase ? 17 : 9;
        for (int kt = kt0; kt < kt1; kt++) {
            h8 af[4];
            if (kt < 16) {
                const int c0 = kt * 16 + q * 4;
#pragma unroll
                for (int mt = 0; mt < 4; mt++) {
                    h4 hs = *(const h4*)(hf + (size_t)sidx[mt] * HIDN + c0);
                    h4 hd = *(const h4*)(hf + (size_t)didx[mt] * HIDN + c0);
                    h8 a;
#pragma unroll
                    for (int u = 0; u < 4; u++) {
                        float x1 = (float)hs[u], x2 = (float)hd[u];
                        a[2 * u]     = (_Float16)(x1 * x2);
                        a[2 * u + 1] = (_Float16)fabsf(x1 - x2);
                    }
                    af[mt] = a;
                }
            } else {
#pragma unroll
                for (int mt = 0; mt < 4; mt++) {
                    h8 a = (h8){0, 0, 0, 0, 0, 0, 0, 0};
                    if (q == 0) {
                        a[0] = (_Float16)(la[mt] + lb[mt]);
                        a[1] = (_Float16)fabsf(la[mt] - lb[mt]);
                    }
                    af[mt] = a;
                }
            }
            const int ko = kt * 32 - kbase + q * 8;
            h8 bf[4];
#pragma unroll
            for (int nt = 0; nt < 4; nt++)
                bf[nt] = *(const h8*)&BtL[(nt * 16 + l15) * 296 + ko];
#pragma unroll
            for (int mt = 0; mt < 4; mt++)
#pragma unroll
                for (int nt = 0; nt < 4; nt++)
                    acc[mt][nt] = __builtin_amdgcn_mfma_f32_16x16x32_f16(af[mt], bf[nt], acc[mt][nt], 0, 0, 0);
        }
    }

    float b1v[4], w2v[4];
#pragma unroll
    for (int nt = 0; nt < 4; nt++) {
        int col = nt * 16 + l15;
        b1v[nt] = eb1[col];
        w2v[nt] = ew2[col];
    }
    const float b2s = eb2[0];
    float part[4][4];
#pragma unroll
    for (int mt = 0; mt < 4; mt++)
#pragma unroll
        for (int reg = 0; reg < 4; reg++) {
            float s = 0.f;
#pragma unroll
            for (int nt = 0; nt < 4; nt++) {
                float v = acc[mt][nt][reg] + b1v[nt];
                s += fmaxf(v, 0.f) * w2v[nt];
            }
            part[mt][reg] = s;
        }
#pragma unroll
    for (int off = 1; off < 16; off <<= 1)
#pragma unroll
        for (int mt = 0; mt < 4; mt++)
#pragma unroll
            for (int reg = 0; reg < 4; reg++)
                part[mt][reg] += __shfl_xor(part[mt][reg], off, 64);
    if (l15 == 0) {
#pragma unroll
        for (int mt = 0; mt < 4; mt++)
#pragma unroll
            for (int reg = 0; reg < 4; reg++) {
                int er = eb + wid * 64 + mt * 16 + q * 4 + reg;
                float xr = part[mt][reg] + b2s;
                w_half[er] = 0.8f / (1.0f + __expf(-xr));
            }
    }
}

// ---------------- symmetrize w + edge norm ----------------
__global__ void k_wsym(const int* __restrict__ ei, const float* __restrict__ w_half,
                       const float* __restrict__ degc, float* __restrict__ wsym,
                       float* __restrict__ enorm) {
    int p = blockIdx.x * 256 + threadIdx.x;
    if (p >= E2P) return;
    wsym[p]  = 0.5f * (w_half[p] + w_half[p + E2P]);
    enorm[p] = rsqrtf(degc[ei[p]] * degc[ei[EDD + p]]);
}

// ---------------- m init: softmax(log_phi[src]) ----------------
__global__ void k_minit(const int* __restrict__ ei, const float* __restrict__ log_phi,
                        float* __restrict__ m) {
    int tid = blockIdx.x * 256 + threadIdx.x;   // grid exact: EDD*8
    int e = tid >> 3, d = tid & 7;
    int sp = ei[e];
    float v = log_phi[(size_t)sp * 8 + d];
    float mx = v;
    mx = fmaxf(mx, __shfl_xor(mx, 1, 64));
    mx = fmaxf(mx, __shfl_xor(mx, 2, 64));
    mx = fmaxf(mx, __shfl_xor(mx, 4, 64));
    float ex = __expf(v - mx);
    float s = ex;
    s += __shfl_xor(s, 1, 64);
    s += __shfl_xor(s, 2, 64);
    s += __shfl_xor(s, 4, 64);
    m[tid] = ex / s;
}

// ---------------- BP scatter: sum_in[dst] += log_f (both directions per pair) ----------------
__global__ void k_bpA(const int* __restrict__ ei, const float* __restrict__ wsym,
                      const float* __restrict__ enorm, const float* __restrict__ Rs,
                      const float* __restrict__ m, float* __restrict__ sum_in) {
    __shared__ float RsL[64];
    if (threadIdx.x < 64) RsL[threadIdx.x] = Rs[threadIdx.x];
    __syncthreads();
    int tid = blockIdx.x * 256 + threadIdx.x;   // grid exact: E2P*8
    int p = tid >> 3, d = tid & 7;
    float w = wsym[p], nrm = enorm[p];
    int sp = ei[p], dp = ei[EDD + p];
    float Kc[8];
#pragma unroll
    for (int c = 0; c < 8; c++) Kc[c] = __expf(w * RsL[c * 8 + d]);
    const f4* mp = (const f4*)(m + (size_t)p * 8);
    f4 a0 = mp[0], a1 = mp[1];
    const f4* mq = (const f4*)(m + (size_t)(p + E2P) * 8);
    f4 b0 = mq[0], b1 = mq[1];
    float fe = a0[0]*Kc[0]+a0[1]*Kc[1]+a0[2]*Kc[2]+a0[3]*Kc[3]
             + a1[0]*Kc[4]+a1[1]*Kc[5]+a1[2]*Kc[6]+a1[3]*Kc[7];
    float fr = b0[0]*Kc[0]+b0[1]*Kc[1]+b0[2]*Kc[2]+b0[3]*Kc[3]
             + b1[0]*Kc[4]+b1[1]*Kc[5]+b1[2]*Kc[6]+b1[3]*Kc[7];
    float lfe = __logf(fmaxf(fe, 1e-12f)) * nrm;
    float lfr = __logf(fmaxf(fr, 1e-12f)) * nrm;
    atomicAdd(&sum_in[(size_t)dp * 8 + d], lfe);
    atomicAdd(&sum_in[(size_t)sp * 8 + d], lfr);
}

// ---------------- BP update: m' for both directions per pair ----------------
__global__ void k_bpB(const int* __restrict__ ei, const float* __restrict__ wsym,
                      const float* __restrict__ enorm, const float* __restrict__ Rs,
                      const float* __restrict__ log_phi, const float* __restrict__ m,
                      const float* __restrict__ sum_in, float* __restrict__ mo) {
    __shared__ float RsL[64];
    if (threadIdx.x < 64) RsL[threadIdx.x] = Rs[threadIdx.x];
    __syncthreads();
    int tid = blockIdx.x * 256 + threadIdx.x;
    int p = tid >> 3, d = tid & 7;
    float w = wsym[p], nrm = enorm[p];
    int sp = ei[p], dp = ei[EDD + p];
    float Kc[8];
#pragma unroll
    for (int c = 0; c < 8; c++) Kc[c] = __expf(w * RsL[c * 8 + d]);
    const f4* mp = (const f4*)(m + (size_t)p * 8);
    f4 a0 = mp[0], a1 = mp[1];
    const f4* mq = (const f4*)(m + (size_t)(p + E2P) * 8);
    f4 b0 = mq[0], b1 = mq[1];
    float fe = a0[0]*Kc[0]+a0[1]*Kc[1]+a0[2]*Kc[2]+a0[3]*Kc[3]
             + a1[0]*Kc[4]+a1[1]*Kc[5]+a1[2]*Kc[6]+a1[3]*Kc[7];
    float fr = b0[0]*Kc[0]+b0[1]*Kc[1]+b0[2]*Kc[2]+b0[3]*Kc[3]
             + b1[0]*Kc[4]+b1[1]*Kc[5]+b1[2]*Kc[6]+b1[3]*Kc[7];
    float lfe = __logf(fmaxf(fe, 1e-12f)) * nrm;
    float lfr = __logf(fmaxf(fr, 1e-12f)) * nrm;
    float alpha = Rs[64];
    float te = log_phi[(size_t)sp * 8 + d] + alpha * (sum_in[(size_t)sp * 8 + d] - lfr);
    float tr = log_phi[(size_t)dp * 8 + d] + alpha * (sum_in[(size_t)dp * 8 + d] - lfe);
    // softmax(te) over the 8-lane group
    float mx = te;
    mx = fmaxf(mx, __shfl_xor(mx, 1, 64));
    mx = fmaxf(mx, __shfl_xor(mx, 2, 64));
    mx = fmaxf(mx, __shfl_xor(mx, 4, 64));
    float ex = __expf(te - mx);
    float s = ex;
    s += __shfl_xor(s, 1, 64); s += __shfl_xor(s, 2, 64); s += __shfl_xor(s, 4, 64);
    float mne = ex / s;
    float mx2 = tr;
    mx2 = fmaxf(mx2, __shfl_xor(mx2, 1, 64));
    mx2 = fmaxf(mx2, __shfl_xor(mx2, 2, 64));
    mx2 = fmaxf(mx2, __shfl_xor(mx2, 4, 64));
    float ex2 = __expf(tr - mx2);
    float s2 = ex2;
    s2 += __shfl_xor(s2, 1, 64); s2 += __shfl_xor(s2, 2, 64); s2 += __shfl_xor(s2, 4, 64);
    float mnr = ex2 / s2;
    float moe = m[(size_t)p * 8 + d];
    float mor = m[(size_t)(p + E2P) * 8 + d];
    float m1 = fmaxf(0.8f * moe + 0.2f * mne, 1e-12f);
    float m2 = fmaxf(0.8f * mor + 0.2f * mnr, 1e-12f);
    float t1 = m1;
    t1 += __shfl_xor(t1, 1, 64); t1 += __shfl_xor(t1, 2, 64); t1 += __shfl_xor(t1, 4, 64);
    float t2 = m2;
    t2 += __shfl_xor(t2, 1, 64); t2 += __shfl_xor(t2, 2, 64); t2 += __shfl_xor(t2, 4, 64);
    mo[(size_t)p * 8 + d] = m1 / t1;
    mo[(size_t)(p + E2P) * 8 + d] = m2 / t2;
}

// ---------------- beliefs = softmax(log_phi + alpha*sum_in) ----------------
__global__ void k_bel(const float* __restrict__ log_phi, const float* __restrict__ sum_in,
                      const float* __restrict__ Rs, float* __restrict__ out) {
    int tid = blockIdx.x * 256 + threadIdx.x;
    if (tid >= NN * 8) return;
    float alpha = Rs[64];
    float v = log_phi[tid] + alpha * sum_in[tid];
    float mx = v;
    mx = fmaxf(mx, __shfl_xor(mx, 1, 64));
    mx = fmaxf(mx, __shfl_xor(mx, 2, 64));
    mx = fmaxf(mx, __shfl_xor(mx, 4, 64));
    float ex = __expf(v - mx);
    float s = ex;
    s += __shfl_xor(s, 1, 64); s += __shfl_xor(s, 2, 64); s += __shfl_xor(s, 4, 64);
    out[tid] = ex / s;
}

extern "C" void kernel_launch(void* const* d_in, const int* in_sizes, int n_in,
                              void* d_out, int out_size, void* d_ws, size_t ws_size,
                              hipStream_t stream) {
    if (ws_size < WS_NEED) return;
    const float* x        = (const float*)d_in[0];
    const int*   ei       = (const int*)d_in[1];
    const float* enc_w1   = (const float*)d_in[3];
    const float* enc_b1   = (const float*)d_in[4];
    const float* enc_w2   = (const float*)d_in[5];
    const float* enc_b2   = (const float*)d_in[6];
    const float* edge_w1  = (const float*)d_in[7];
    const float* edge_b1  = (const float*)d_in[8];
    const float* edge_w2  = (const float*)d_in[9];
    const float* edge_b2  = (const float*)d_in[10];
    const float* R_raw    = (const float*)d_in[11];
    const float* Rsl      = (const float*)d_in[12];
    const float* mlog     = (const float*)d_in[13];

    char* ws = (char*)d_ws;
    _Float16* hf     = (_Float16*)(ws + OFF_HF16);
    float* log_phi   = (float*)(ws + OFF_LOGPHI);
    int*   deg       = (int*)  (ws + OFF_DEG);
    float* logdeg    = (float*)(ws + OFF_LOGDEG);
    float* degc      = (float*)(ws + OFF_DEGC);
    _Float16* Wt     = (_Float16*)(ws + OFF_WT);
    _Float16* Bt     = (_Float16*)(ws + OFF_BT);
    float* Rs        = (float*)(ws + OFF_RS);
    float* w_half    = (float*)(ws + OFF_WHALF);
    float* wsym      = (float*)(ws + OFF_WSYM);
    float* enorm     = (float*)(ws + OFF_ENORM);
    float* mA        = (float*)(ws + OFF_MA);
    float* mB        = (float*)(ws + OFF_MB);
    float* sum_in    = (float*)(ws + OFF_SUMIN);

    hipMemsetAsync(deg, 0, (size_t)NN * 4, stream);
    k_deg<<<dim3(EDD / 256), dim3(256), 0, stream>>>(ei, deg);
    k_node<<<dim3((NN + 255) / 256), dim3(256), 0, stream>>>(deg, logdeg, degc);
    k_prep<<<dim3((256 * 512 + 64 * 544 + 65 + 255) / 256), dim3(256), 0, stream>>>(
        enc_w1, edge_w1, R_raw, Rsl, mlog, Wt, Bt, Rs);
    k_enc<<<dim3((NN + 63) / 64), dim3(256), 0, stream>>>(x, Wt, enc_b1, hf);
    k_logits<<<dim3((NN + 255) / 256), dim3(256), 0, stream>>>(hf, enc_w2, enc_b2, log_phi);
    k_edge<<<dim3(EDD / 256), dim3(256), 0, stream>>>(ei, hf, logdeg, Bt, edge_b1,
                                                      edge_w2, edge_b2, w_half);
    k_wsym<<<dim3((E2P + 255) / 256), dim3(256), 0, stream>>>(ei, w_half, degc, wsym, enorm);
    k_minit<<<dim3(EDD * 8 / 256), dim3(256), 0, stream>>>(ei, log_phi, mA);

    float* mc = mA;
    float* mn = mB;
    for (int t = 0; t < 10; t++) {
        hipMemsetAsync(sum_in, 0, (size_t)NN * 8 * 4, stream);
        k_bpA<<<dim3(E2P * 8 / 256), dim3(256), 0, stream>>>(ei, wsym, enorm, Rs, mc, sum_in);
        k_bpB<<<dim3(E2P * 8 / 256), dim3(256), 0, stream>>>(ei, wsym, enorm, Rs, log_phi,
                                                             mc, sum_in, mn);
        float* tmp = mc; mc = mn; mn = tmp;
    }
    hipMemsetAsync(sum_in, 0, (size_t)NN * 8 * 4, stream);
    k_bpA<<<dim3(E2P * 8 / 256), dim3(256), 0, stream>>>(ei, wsym, enorm, Rs, mc, sum_in);
    k_bel<<<dim3((NN * 8 + 255) / 256), dim3(256), 0, stream>>>(log_phi, sum_in, Rs,
                                                                (float*)d_out);
    (void)in_sizes; (void)n_in; (void)out_size;
}

// Round 2
// 932.517 us; speedup vs baseline: 1.3016x; 1.3016x over previous
//
#include <hip/hip_runtime.h>
#include <cstddef>
#include <cstdint>

typedef _Float16 h4 __attribute__((ext_vector_type(4)));
typedef _Float16 h8 __attribute__((ext_vector_type(8)));
typedef float    f4 __attribute__((ext_vector_type(4)));

#define NN      50000
#define IND     512
#define HIDN    256
#define E2P     400000
#define EDD     800000

// ---- workspace layout (bytes) ----
#define OFF_HF16    ((size_t)0)            // 25,600,000  f16 h [NN][256]
#define OFF_LOGPHI  ((size_t)25600000)     //  1,600,000  f32 [NN][8]
#define OFF_DEG     ((size_t)27200000)     //    200,000  int [NN]
#define OFF_LOGDEG  ((size_t)27400000)     //    200,000  f32
#define OFF_DEGC    ((size_t)27600000)     //    200,000  f32
#define OFF_WT      ((size_t)27800000)     //    262,144  f16 enc_w1^T [256][512]
#define OFF_BT      ((size_t)28062144)     //     69,632  f16 edge_w1 perm^T [64][544]
#define OFF_RS      ((size_t)28131776)     //        512  f32 Rs[64] + alpha at [64]
#define OFF_WSYM    ((size_t)28132288)     //  1,600,000  f32 [E2P]  (== w, exact symmetry)
#define OFF_ENORM   ((size_t)29732288)     //  1,600,000  f32 [E2P]
#define OFF_MA      ((size_t)31332288)     // 25,600,000  f32 [EDD][8]
#define OFF_MB      ((size_t)56932288)     // 25,600,000
#define OFF_SA      ((size_t)82532288)     //  1,600,000  f32 [NN][8]
#define OFF_SB      ((size_t)84132288)     //  1,600,000
#define WS_NEED     ((size_t)85732288)

// ---------------- degree count ----------------
__global__ void k_deg(const int* __restrict__ ei, int* __restrict__ deg) {
    int e = blockIdx.x * 256 + threadIdx.x;   // grid exact: EDD
    atomicAdd(&deg[ei[e]], 1);
}

__global__ void k_node(const int* __restrict__ deg, float* __restrict__ logdeg,
                       float* __restrict__ degc) {
    int n = blockIdx.x * 256 + threadIdx.x;
    if (n < NN) {
        float d = (float)deg[n];
        logdeg[n] = logf(d + 1.0f);
        degc[n]   = fmaxf(d, 1.0f);
    }
}

// ---------------- weight prep: transpose/permute/cast + R + alpha ----------------
__global__ void k_prep(const float* __restrict__ enc_w1, const float* __restrict__ edge_w1,
                       const float* __restrict__ R_raw, const float* __restrict__ Rsl,
                       const float* __restrict__ mlog,
                       _Float16* __restrict__ Wt, _Float16* __restrict__ Bt,
                       float* __restrict__ Rs) {
    int gid = blockIdx.x * 256 + threadIdx.x;
    if (gid < 256 * 512) {                       // Wt[n][k] = enc_w1[k][n]
        int n = gid >> 9, k = gid & 511;
        Wt[n * 512 + k] = (_Float16)enc_w1[k * 256 + n];
        return;
    }
    int g2 = gid - 256 * 512;
    if (g2 < 64 * 544) {                         // Bt[n][k'] with interleaved K perm
        int n = g2 / 544, k = g2 - n * 544;
        float v = 0.0f;
        if (k < 512) {
            int orig = (k & 1) ? 256 + (k >> 1) : (k >> 1);
            v = edge_w1[orig * 64 + n];
        } else if (k < 514) {
            v = edge_w1[k * 64 + n];
        }
        Bt[n * 544 + k] = (_Float16)v;
        return;
    }
    int g3 = g2 - 64 * 544;
    if (g3 < 64) {
        int c = g3 >> 3, d = g3 & 7;
        float rv = 0.5f * (R_raw[c * 8 + d] + R_raw[d * 8 + c]);
        float s  = log1pf(expf(Rsl[0])) + 1e-6f; // softplus + eps
        Rs[g3] = s * tanhf(rv);
        return;
    }
    if (g3 == 64) {
        Rs[64] = 1.5f / (1.0f + expf(-mlog[0])); // alpha = ALPHA_MAX*sigmoid(msg_logit)
    }
}

// ---------------- encoder layer 1: h = relu(x @ enc_w1 + b1), f16 MFMA ----------------
__global__ __launch_bounds__(256) void k_enc(const float* __restrict__ x,
                                             const _Float16* __restrict__ Wt,
                                             const float* __restrict__ b1,
                                             _Float16* __restrict__ hf) {
    __shared__ _Float16 XL[64 * 40];
    __shared__ _Float16 WL[256 * 40];
    const int tid = threadIdx.x;
    const int wid = tid >> 6;
    const int lane = tid & 63;
    const int l15 = lane & 15;
    const int q = lane >> 4;
    const int m0 = blockIdx.x * 64;

    f4 acc[16];
#pragma unroll
    for (int i = 0; i < 16; i++) acc[i] = (f4){0.f, 0.f, 0.f, 0.f};

    const int xr = tid >> 2;
    const int xs = tid & 3;
    const int gr = m0 + xr;

    for (int kt = 0; kt < 16; kt++) {
        __syncthreads();
        f4 xv0 = (f4){0, 0, 0, 0}, xv1 = (f4){0, 0, 0, 0};
        if (gr < NN) {
            const f4* xp = (const f4*)(x + (size_t)gr * IND + kt * 32 + xs * 8);
            xv0 = xp[0]; xv1 = xp[1];
        }
        h8 xh;
#pragma unroll
        for (int u = 0; u < 4; u++) { xh[u] = (_Float16)xv0[u]; xh[4 + u] = (_Float16)xv1[u]; }
        *(h8*)&XL[xr * 40 + xs * 8] = xh;
#pragma unroll
        for (int rep = 0; rep < 4; rep++) {
            int cid = rep * 256 + tid;
            int n = cid >> 2;
            int off = (cid & 3) * 8;
            h8 wv = *(const h8*)(Wt + (size_t)n * IND + kt * 32 + off);
            *(h8*)&WL[n * 40 + off] = wv;
        }
        __syncthreads();
        h8 a = *(const h8*)&XL[(wid * 16 + l15) * 40 + q * 8];
#pragma unroll
        for (int nt = 0; nt < 16; nt++) {
            h8 b = *(const h8*)&WL[(nt * 16 + l15) * 40 + q * 8];
            acc[nt] = __builtin_amdgcn_mfma_f32_16x16x32_f16(a, b, acc[nt], 0, 0, 0);
        }
    }
#pragma unroll
    for (int nt = 0; nt < 16; nt++) {
        int col = nt * 16 + l15;
        float bv = b1[col];
#pragma unroll
        for (int reg = 0; reg < 4; reg++) {
            int row = m0 + wid * 16 + q * 4 + reg;
            if (row < NN) {
                float v = acc[nt][reg] + bv;
                hf[(size_t)row * HIDN + col] = (_Float16)fmaxf(v, 0.f);
            }
        }
    }
}

// ---------------- encoder layer 2 + log_softmax, thread per node ----------------
__global__ void k_logits(const _Float16* __restrict__ hf, const float* __restrict__ w2,
                         const float* __restrict__ b2, float* __restrict__ log_phi) {
    __shared__ float w2L[2048];
    for (int i = threadIdx.x; i < 2048; i += 256) w2L[i] = w2[i];
    __syncthreads();
    int n = blockIdx.x * 256 + threadIdx.x;
    if (n >= NN) return;
    float sum[8];
#pragma unroll
    for (int c = 0; c < 8; c++) sum[c] = b2[c];
    for (int kb = 0; kb < 32; kb++) {
        h8 hv = *(const h8*)(hf + (size_t)n * HIDN + kb * 8);
#pragma unroll
        for (int u = 0; u < 8; u++) {
            float hx = (float)hv[u];
            const float* wr = &w2L[(kb * 8 + u) * 8];
#pragma unroll
            for (int c = 0; c < 8; c++) sum[c] += hx * wr[c];
        }
    }
    float mx = sum[0];
#pragma unroll
    for (int c = 1; c < 8; c++) mx = fmaxf(mx, sum[c]);
    float se = 0.f;
#pragma unroll
    for (int c = 0; c < 8; c++) se += __expf(sum[c] - mx);
    float lse = __logf(se);
#pragma unroll
    for (int c = 0; c < 8; c++) log_phi[(size_t)n * 8 + c] = sum[c] - mx - lse;
}

// ---------------- edge MLP on UNDIRECTED PAIRS ONLY (w is exactly symmetric) ----------------
// 4-phase B staging: LDS 64x168 halfs = 21.5 KB -> ~6-7 blocks/CU
__global__ __launch_bounds__(256) void k_edge(const int* __restrict__ ei,
        const _Float16* __restrict__ hf, const float* __restrict__ logdeg,
        const _Float16* __restrict__ BtG, const float* __restrict__ eb1,
        const float* __restrict__ ew2, const float* __restrict__ eb2,
        float* __restrict__ wsym) {
    __shared__ _Float16 BtL[64 * 168];
    const int tid = threadIdx.x;
    const int wid = tid >> 6;
    const int lane = tid & 63;
    const int l15 = lane & 15;
    const int q = lane >> 4;
    const int eb = blockIdx.x * 256;

    int sidx[4], didx[4];
    float la[4], lb[4];
#pragma unroll
    for (int mt = 0; mt < 4; mt++) {
        int e = eb + wid * 64 + mt * 16 + l15;
        int ee = (e < E2P) ? e : 0;
        sidx[mt] = ei[ee];
        didx[mt] = ei[EDD + ee];
        la[mt] = logdeg[sidx[mt]];
        lb[mt] = logdeg[didx[mt]];
    }

    f4 acc[4][4];
#pragma unroll
    for (int a = 0; a < 4; a++)
#pragma unroll
        for (int b = 0; b < 4; b++) acc[a][b] = (f4){0.f, 0.f, 0.f, 0.f};

    for (int ph = 0; ph < 4; ph++) {
        const int kbase = ph * 160;
        const int nch = (ph == 3) ? 8 : 20;      // 8-half chunks per row this phase
        __syncthreads();
        {
            const int r = tid & 63;
            const int cb = tid >> 6;
            for (int ck = cb; ck < nch; ck += 4) {
                h8 v = *(const h8*)(BtG + (size_t)r * 544 + kbase + ck * 8);
                *(h8*)&BtL[r * 168 + ck * 8] = v;
            }
        }
        __syncthreads();
        const int kt0 = ph * 5;
        const int kt1 = (ph == 3) ? 17 : kt0 + 5;
        for (int kt = kt0; kt < kt1; kt++) {
            h8 af[4];
            if (kt < 16) {
                const int c0 = kt * 16 + q * 4;
#pragma unroll
                for (int mt = 0; mt < 4; mt++) {
                    h4 hs = *(const h4*)(hf + (size_t)sidx[mt] * HIDN + c0);
                    h4 hd = *(const h4*)(hf + (size_t)didx[mt] * HIDN + c0);
                    h8 a;
#pragma unroll
                    for (int u = 0; u < 4; u++) {
                        float x1 = (float)hs[u], x2 = (float)hd[u];
                        a[2 * u]     = (_Float16)(x1 * x2);
                        a[2 * u + 1] = (_Float16)fabsf(x1 - x2);
                    }
                    af[mt] = a;
                }
            } else {
#pragma unroll
                for (int mt = 0; mt < 4; mt++) {
                    h8 a = (h8){0, 0, 0, 0, 0, 0, 0, 0};
                    if (q == 0) {
                        a[0] = (_Float16)(la[mt] + lb[mt]);
                        a[1] = (_Float16)fabsf(la[mt] - lb[mt]);
                    }
                    af[mt] = a;
                }
            }
            const int ko = kt * 32 - kbase + q * 8;
            h8 bf[4];
#pragma unroll
            for (int nt = 0; nt < 4; nt++)
                bf[nt] = *(const h8*)&BtL[(nt * 16 + l15) * 168 + ko];
#pragma unroll
            for (int mt = 0; mt < 4; mt++)
#pragma unroll
                for (int nt = 0; nt < 4; nt++)
                    acc[mt][nt] = __builtin_amdgcn_mfma_f32_16x16x32_f16(af[mt], bf[nt], acc[mt][nt], 0, 0, 0);
        }
    }

    float b1v[4], w2v[4];
#pragma unroll
    for (int nt = 0; nt < 4; nt++) {
        int col = nt * 16 + l15;
        b1v[nt] = eb1[col];
        w2v[nt] = ew2[col];
    }
    const float b2s = eb2[0];
    float part[4][4];
#pragma unroll
    for (int mt = 0; mt < 4; mt++)
#pragma unroll
        for (int reg = 0; reg < 4; reg++) {
            float s = 0.f;
#pragma unroll
            for (int nt = 0; nt < 4; nt++) {
                float v = acc[mt][nt][reg] + b1v[nt];
                s += fmaxf(v, 0.f) * w2v[nt];
            }
            part[mt][reg] = s;
        }
#pragma unroll
    for (int off = 1; off < 16; off <<= 1)
#pragma unroll
        for (int mt = 0; mt < 4; mt++)
#pragma unroll
            for (int reg = 0; reg < 4; reg++)
                part[mt][reg] += __shfl_xor(part[mt][reg], off, 64);
    if (l15 == 0) {
#pragma unroll
        for (int mt = 0; mt < 4; mt++)
#pragma unroll
            for (int reg = 0; reg < 4; reg++) {
                int er = eb + wid * 64 + mt * 16 + q * 4 + reg;
                if (er < E2P) {
                    float xr = part[mt][reg] + b2s;
                    wsym[er] = 0.8f / (1.0f + __expf(-xr));
                }
            }
    }
}

// ---------------- fused m-init + first scatter (+ enorm) ----------------
__global__ void k_init(const int* __restrict__ ei, const float* __restrict__ wsymb,
                       const float* __restrict__ degc, const float* __restrict__ Rs,
                       const float* __restrict__ log_phi,
                       float* __restrict__ m, float* __restrict__ enorm,
                       float* __restrict__ S) {
    __shared__ float RsL[64];
    if (threadIdx.x < 64) RsL[threadIdx.x] = Rs[threadIdx.x];
    __syncthreads();
    int tid = blockIdx.x * 256 + threadIdx.x;   // grid exact: E2P*8
    int p = tid >> 3, d = tid & 7;
    int lane = threadIdx.x & 63;
    int gb = lane & 56;
    int sp = ei[p], dp = ei[EDD + p];
    float w = wsymb[p];
    float nrm = rsqrtf(degc[sp] * degc[dp]);
    if (d == 0) enorm[p] = nrm;
    float Kc[8];
#pragma unroll
    for (int c = 0; c < 8; c++) Kc[c] = __expf(w * RsL[c * 8 + d]);
    float vs = log_phi[(size_t)sp * 8 + d];
    float vd = log_phi[(size_t)dp * 8 + d];
    // softmax over 8-lane group
    float mx = vs;
    mx = fmaxf(mx, __shfl_xor(mx, 1, 64));
    mx = fmaxf(mx, __shfl_xor(mx, 2, 64));
    mx = fmaxf(mx, __shfl_xor(mx, 4, 64));
    float ex = __expf(vs - mx);
    float s = ex;
    s += __shfl_xor(s, 1, 64); s += __shfl_xor(s, 2, 64); s += __shfl_xor(s, 4, 64);
    float me = ex / s;
    float mx2 = vd;
    mx2 = fmaxf(mx2, __shfl_xor(mx2, 1, 64));
    mx2 = fmaxf(mx2, __shfl_xor(mx2, 2, 64));
    mx2 = fmaxf(mx2, __shfl_xor(mx2, 4, 64));
    float ex2 = __expf(vd - mx2);
    float s2 = ex2;
    s2 += __shfl_xor(s2, 1, 64); s2 += __shfl_xor(s2, 2, 64); s2 += __shfl_xor(s2, 4, 64);
    float mr = ex2 / s2;
    m[(size_t)p * 8 + d] = me;
    m[(size_t)(E2P + p) * 8 + d] = mr;
    float fe = 0.f, fr = 0.f;
#pragma unroll
    for (int c = 0; c < 8; c++) {
        fe += __shfl(me, gb | c, 64) * Kc[c];
        fr += __shfl(mr, gb | c, 64) * Kc[c];
    }
    float lfe = __logf(fmaxf(fe, 1e-12f)) * nrm;
    float lfr = __logf(fmaxf(fr, 1e-12f)) * nrm;
    atomicAdd(&S[(size_t)dp * 8 + d], lfe);
    atomicAdd(&S[(size_t)sp * 8 + d], lfr);
}

// ---------------- fused BP step: update m AND scatter new log_f into S_next ----------------
__global__ void k_bpF(const int* __restrict__ ei, const float* __restrict__ wsymb,
                      const float* __restrict__ enorm, const float* __restrict__ Rs,
                      const float* __restrict__ log_phi, const float* __restrict__ m,
                      const float* __restrict__ S, float* __restrict__ mo,
                      float* __restrict__ Sn) {
    __shared__ float RsL[64];
    if (threadIdx.x < 64) RsL[threadIdx.x] = Rs[threadIdx.x];
    __syncthreads();
    int tid = blockIdx.x * 256 + threadIdx.x;   // grid exact: E2P*8
    int p = tid >> 3, d = tid & 7;
    int lane = threadIdx.x & 63;
    int gb = lane & 56;
    int sp = ei[p], dp = ei[EDD + p];
    float w = wsymb[p], nrm = enorm[p];
    float Kc[8];
#pragma unroll
    for (int c = 0; c < 8; c++) Kc[c] = __expf(w * RsL[c * 8 + d]);
    float me = m[(size_t)p * 8 + d];
    float mr = m[(size_t)(E2P + p) * 8 + d];
    float fe = 0.f, fr = 0.f;
#pragma unroll
    for (int c = 0; c < 8; c++) {
        fe += __shfl(me, gb | c, 64) * Kc[c];
        fr += __shfl(mr, gb | c, 64) * Kc[c];
    }
    float lfe = __logf(fmaxf(fe, 1e-12f)) * nrm;
    float lfr = __logf(fmaxf(fr, 1e-12f)) * nrm;
    float lps = log_phi[(size_t)sp * 8 + d];
    float lpd = log_phi[(size_t)dp * 8 + d];
    float se = S[(size_t)sp * 8 + d];
    float sd = S[(size_t)dp * 8 + d];
    float alpha = Rs[64];
    float te = lps + alpha * (se - lfr);
    float tr = lpd + alpha * (sd - lfe);
    // softmax over 8-lane group
    float mx = te;
    mx = fmaxf(mx, __shfl_xor(mx, 1, 64));
    mx = fmaxf(mx, __shfl_xor(mx, 2, 64));
    mx = fmaxf(mx, __shfl_xor(mx, 4, 64));
    float ex = __expf(te - mx);
    float s = ex;
    s += __shfl_xor(s, 1, 64); s += __shfl_xor(s, 2, 64); s += __shfl_xor(s, 4, 64);
    float mne = ex / s;
    float mx2 = tr;
    mx2 = fmaxf(mx2, __shfl_xor(mx2, 1, 64));
    mx2 = fmaxf(mx2, __shfl_xor(mx2, 2, 64));
    mx2 = fmaxf(mx2, __shfl_xor(mx2, 4, 64));
    float ex2 = __expf(tr - mx2);
    float s2 = ex2;
    s2 += __shfl_xor(s2, 1, 64); s2 += __shfl_xor(s2, 2, 64); s2 += __shfl_xor(s2, 4, 64);
    float mnr = ex2 / s2;
    float m1 = fmaxf(0.8f * me + 0.2f * mne, 1e-12f);
    float m2 = fmaxf(0.8f * mr + 0.2f * mnr, 1e-12f);
    float t1 = m1;
    t1 += __shfl_xor(t1, 1, 64); t1 += __shfl_xor(t1, 2, 64); t1 += __shfl_xor(t1, 4, 64);
    float t2 = m2;
    t2 += __shfl_xor(t2, 1, 64); t2 += __shfl_xor(t2, 2, 64); t2 += __shfl_xor(t2, 4, 64);
    float m1n = m1 / t1;
    float m2n = m2 / t2;
    mo[(size_t)p * 8 + d] = m1n;
    mo[(size_t)(E2P + p) * 8 + d] = m2n;
    // scatter NEW messages into S_next (fused next-iteration bpA)
    float fe2 = 0.f, fr2 = 0.f;
#pragma unroll
    for (int c = 0; c < 8; c++) {
        fe2 += __shfl(m1n, gb | c, 64) * Kc[c];
        fr2 += __shfl(m2n, gb | c, 64) * Kc[c];
    }
    float lfe2 = __logf(fmaxf(fe2, 1e-12f)) * nrm;
    float lfr2 = __logf(fmaxf(fr2, 1e-12f)) * nrm;
    atomicAdd(&Sn[(size_t)dp * 8 + d], lfe2);
    atomicAdd(&Sn[(size_t)sp * 8 + d], lfr2);
}

// ---------------- beliefs = softmax(log_phi + alpha*sum_in) ----------------
__global__ void k_bel(const float* __restrict__ log_phi, const float* __restrict__ sum_in,
                      const float* __restrict__ Rs, float* __restrict__ out) {
    int tid = blockIdx.x * 256 + threadIdx.x;
    if (tid >= NN * 8) return;
    float alpha = Rs[64];
    float v = log_phi[tid] + alpha * sum_in[tid];
    float mx = v;
    mx = fmaxf(mx, __shfl_xor(mx, 1, 64));
    mx = fmaxf(mx, __shfl_xor(mx, 2, 64));
    mx = fmaxf(mx, __shfl_xor(mx, 4, 64));
    float ex = __expf(v - mx);
    float s = ex;
    s += __shfl_xor(s, 1, 64); s += __shfl_xor(s, 2, 64); s += __shfl_xor(s, 4, 64);
    out[tid] = ex / s;
}

extern "C" void kernel_launch(void* const* d_in, const int* in_sizes, int n_in,
                              void* d_out, int out_size, void* d_ws, size_t ws_size,
                              hipStream_t stream) {
    if (ws_size < WS_NEED) return;
    const float* x        = (const float*)d_in[0];
    const int*   ei       = (const int*)d_in[1];
    const float* enc_w1   = (const float*)d_in[3];
    const float* enc_b1   = (const float*)d_in[4];
    const float* enc_w2   = (const float*)d_in[5];
    const float* enc_b2   = (const float*)d_in[6];
    const float* edge_w1  = (const float*)d_in[7];
    const float* edge_b1  = (const float*)d_in[8];
    const float* edge_w2  = (const float*)d_in[9];
    const float* edge_b2  = (const float*)d_in[10];
    const float* R_raw    = (const float*)d_in[11];
    const float* Rsl      = (const float*)d_in[12];
    const float* mlog     = (const float*)d_in[13];

    char* ws = (char*)d_ws;
    _Float16* hf     = (_Float16*)(ws + OFF_HF16);
    float* log_phi   = (float*)(ws + OFF_LOGPHI);
    int*   deg       = (int*)  (ws + OFF_DEG);
    float* logdeg    = (float*)(ws + OFF_LOGDEG);
    float* degc      = (float*)(ws + OFF_DEGC);
    _Float16* Wt     = (_Float16*)(ws + OFF_WT);
    _Float16* Bt     = (_Float16*)(ws + OFF_BT);
    float* Rs        = (float*)(ws + OFF_RS);
    float* wsym      = (float*)(ws + OFF_WSYM);
    float* enorm     = (float*)(ws + OFF_ENORM);
    float* mA        = (float*)(ws + OFF_MA);
    float* mB        = (float*)(ws + OFF_MB);
    float* SA        = (float*)(ws + OFF_SA);
    float* SB        = (float*)(ws + OFF_SB);

    hipMemsetAsync(deg, 0, (size_t)NN * 4, stream);
    k_deg<<<dim3(EDD / 256), dim3(256), 0, stream>>>(ei, deg);
    k_node<<<dim3((NN + 255) / 256), dim3(256), 0, stream>>>(deg, logdeg, degc);
    k_prep<<<dim3((256 * 512 + 64 * 544 + 65 + 255) / 256), dim3(256), 0, stream>>>(
        enc_w1, edge_w1, R_raw, Rsl, mlog, Wt, Bt, Rs);
    k_enc<<<dim3((NN + 63) / 64), dim3(256), 0, stream>>>(x, Wt, enc_b1, hf);
    k_logits<<<dim3((NN + 255) / 256), dim3(256), 0, stream>>>(hf, enc_w2, enc_b2, log_phi);
    k_edge<<<dim3((E2P + 255) / 256), dim3(256), 0, stream>>>(ei, hf, logdeg, Bt, edge_b1,
                                                              edge_w2, edge_b2, wsym);
    hipMemsetAsync(SA, 0, (size_t)NN * 8 * 4, stream);
    k_init<<<dim3(E2P * 8 / 256), dim3(256), 0, stream>>>(ei, wsym, degc, Rs, log_phi,
                                                          mA, enorm, SA);
    float* mc = mA; float* mn = mB;
    float* Sc = SA; float* Sx = SB;
    for (int t = 0; t < 10; t++) {
        hipMemsetAsync(Sx, 0, (size_t)NN * 8 * 4, stream);
        k_bpF<<<dim3(E2P * 8 / 256), dim3(256), 0, stream>>>(ei, wsym, enorm, Rs, log_phi,
                                                             mc, Sc, mn, Sx);
        float* tmp = mc; mc = mn; mn = tmp;
        tmp = Sc; Sc = Sx; Sx = tmp;
    }
    k_bel<<<dim3((NN * 8 + 255) / 256), dim3(256), 0, stream>>>(log_phi, Sc, Rs,
                                                                (float*)d_out);
    (void)in_sizes; (void)n_in; (void)out_size;
}